// Round 21
// baseline (414.954 us; speedup 1.0000x reference)
//
#include <hip/hip_runtime.h>
#include <hip/hip_bf16.h>
#include <stdint.h>

#define Bb 2
#define Ss 2048
#define Hh 4096
#define NHh 32
#define HDd 128
#define KVHh 2

typedef __attribute__((ext_vector_type(8))) short bf16x8;
typedef __attribute__((ext_vector_type(4))) float f32x4;
typedef __attribute__((ext_vector_type(16))) float f32x16;
typedef __attribute__((ext_vector_type(4))) unsigned int u32x4;
typedef unsigned short u16;
typedef unsigned int u32;
typedef unsigned long long u64;

__device__ __forceinline__ u16 f2b(float f) {
  union { float f; u32 u; } v; v.f = f;
  u32 r = v.u + 0x7fffu + ((v.u >> 16) & 1u);
  return (u16)(r >> 16);
}
__device__ __forceinline__ float b2f(u16 h) {
  union { u32 u; float f; } v; v.u = ((u32)h) << 16;
  return v.f;
}

__device__ __forceinline__ u32 cvtpk(float lo, float hi_) {
  u32 r;
  asm("v_cvt_pk_bf16_f32 %0, %1, %2" : "=v"(r) : "v"(lo), "v"(hi_));
  return r;
}
__device__ __forceinline__ void plswap(u32& x, u32& y) {
  asm volatile("v_permlane32_swap_b32 %0, %1" : "+v"(x), "+v"(y));
}

// async global->LDS, 16B per lane; LDS dest is wave-uniform base + lane*16
__device__ __forceinline__ void gload_lds16(const u16* g, u16* l) {
  __builtin_amdgcn_global_load_lds(
      (const __attribute__((address_space(1))) u32*)(uintptr_t)g,
      (__attribute__((address_space(3))) u32*)(u32)(uintptr_t)l,
      16, 0, 0);
}

// ---------------- fused f32 -> bf16 convert: hidden + Wqkv ----------------
__global__ void cvt2_k(const float* __restrict__ a, u16* __restrict__ oa,
                       const float* __restrict__ b, u16* __restrict__ ob) {
  int i = blockIdx.x * blockDim.x + threadIdx.x;
  const float* src;
  u16* dst;
  int off;
  if (i < 4194304) { src = a; dst = oa; off = i; }
  else { src = b; dst = ob; off = i - 4194304; }
  int idx = off * 4;
  float4 v = *(const float4*)&src[idx];
  u64 pack = (u64)f2b(v.x) | ((u64)f2b(v.y) << 16) |
             ((u64)f2b(v.z) << 32) | ((u64)f2b(v.w) << 48);
  *(u64*)&dst[idx] = pack;
}

// ---------------- f32 -> bf16 convert (Wdense, after QKV GEMM) ----------
__global__ void cvtW_k(const float* __restrict__ in, u16* __restrict__ out) {
  int i = blockIdx.x * blockDim.x + threadIdx.x;
  int idx = i * 4;
  float4 v = *(const float4*)&in[idx];
  u64 pack = (u64)f2b(v.x) | ((u64)f2b(v.y) << 16) |
             ((u64)f2b(v.z) << 32) | ((u64)f2b(v.w) << 48);
  *(u64*)&out[idx] = pack;
}

// ---------------- RoPE in-place on (B, nheads, S, HD) bf16 — K only ----------------
__global__ void rope_k(u16* __restrict__ X, const float* __restrict__ rope, int nheads) {
  int i = blockIdx.x * blockDim.x + threadIdx.x;
  int p = i & 31;
  int s = (i >> 5) & (Ss - 1);
  int bh = i >> 16;
  if (bh >= Bb * nheads) return;
  int b = bh / nheads;
  size_t base = ((size_t)bh * Ss + s) * HDd + p * 2;
  u32 x01 = *(u32*)&X[base];
  float x0 = b2f((u16)(x01 & 0xffff));
  float x1 = b2f((u16)(x01 >> 16));
  float2 rc = *(const float2*)&rope[(((size_t)b * Ss + s) * 32 + p) * 2];
  float o0 = x0 * rc.x - x1 * rc.y;
  float o1 = x1 * rc.x + x0 * rc.y;
  u32 o = (u32)f2b(o0) | ((u32)f2b(o1) << 16);
  *(u32*)&X[base] = o;
}

// ---------------- QKV GEMM: 256x256 d256 schedule + fused KV side-work --------------
// (R20-proven: 166 us/dispatch, MfmaUtil 39%.) Q-part: 4096x4096 -> 256 blocks,
// 1/CU, zero tail. KV fused as side-work: block (mtile,ntile) computes KV cols
// [ntile*32,+32) for its 256 A-rows; B_kv staged 2-tiles-per-even-kt; boundary
// vmcnt(5) even kt / vmcnt(4) odd kt.
__global__ __launch_bounds__(512, 2) void gemm_qkv256(
    const u16* __restrict__ A, const u16* __restrict__ Bm,
    const float* __restrict__ bias,
    u16* __restrict__ Qb, u16* __restrict__ Kb, u16* __restrict__ Vb) {
  __shared__ u16 SM[2][4][8192];    // [buf][Bh0,Bh1,Ah0,Ah1][128x64 bf16] 128KB
  __shared__ u16 BKV[2][4096];      // [parity][2 tiles x 32 x 64]          16KB
  const int tid = threadIdx.x;
  const int wave = tid >> 6;
  const int lane = tid & 63;
  const int lr = lane & 15;
  const int lk = lane >> 4;
  const int wr = wave >> 2;          // 0..1 (M half)
  const int wc = wave & 3;           // 0..3 (N quarter; also KV row-group)
  const int bid = blockIdx.x;
  const int xcd = bid & 7;
  const int local = bid >> 3;
  const int m0 = ((xcd >> 2) * 8 + (local >> 2)) * 256;
  const int ntile = (xcd & 3) * 4 + (local & 3);
  const int n0 = ntile * 256;
  const int NT = 64;

  f32x4 acc[8][4];
#pragma unroll
  for (int i = 0; i < 8; ++i)
#pragma unroll
    for (int j = 0; j < 4; ++j) acc[i][j] = (f32x4){0.f, 0.f, 0.f, 0.f};
  f32x4 acckv[2][2];
#pragma unroll
  for (int i = 0; i < 2; ++i)
#pragma unroll
    for (int j = 0; j < 2; ++j) acckv[i][j] = (f32x4){0.f, 0.f, 0.f, 0.f};

  auto stage_half = [&](const u16* grows, int j, u16* dst) {
    if (j >= NT) return;
#pragma unroll
    for (int li = 0; li < 2; ++li) {
      int t16 = li * 512 + tid;
      int row = t16 >> 3, c = t16 & 7;
      int cs = c ^ (row & 7);
      gload_lds16(grows + (size_t)row * 4096 + j * 64 + cs * 8, dst + t16 * 8);
    }
  };
  const u16* Ah0g = A + (size_t)m0 * 4096;
  const u16* Ah1g = A + (size_t)(m0 + 128) * 4096;
  const u16* Bh0g = Bm + (size_t)n0 * 4096;
  const u16* Bh1g = Bm + (size_t)(n0 + 128) * 4096;
  const u16* KVg = Bm + (size_t)(4096 + ntile * 32) * 4096;

  auto stage_bkv = [&](int j2) {
    if (j2 >= NT) return;
    int sub = tid >> 8;                // 0..1
    int idx = tid & 255;
    int row = idx >> 3, c = idx & 7;
    int cs = c ^ (row & 7);
    gload_lds16(KVg + (size_t)row * 4096 + (j2 + sub) * 64 + cs * 8,
                &BKV[(j2 >> 1) & 1][sub * 2048] + idx * 8);
  };

  stage_half(Ah0g, 0, &SM[0][2][0]);
  stage_half(Ah1g, 0, &SM[0][3][0]);
  stage_half(Bh0g, 0, &SM[0][0][0]);
  stage_half(Bh1g, 0, &SM[0][1][0]);
  stage_half(Bh0g, 1, &SM[1][0][0]);
  stage_half(Bh1g, 1, &SM[1][1][0]);
  stage_bkv(0);
  asm volatile("s_waitcnt vmcnt(0)");
  __builtin_amdgcn_s_barrier();
  __builtin_amdgcn_sched_barrier(0);

  for (int kt = 0; kt < NT; ++kt) {
    const int cur = kt & 1;
    const int nxt = cur ^ 1;
    const u16* Ahl = &SM[cur][2 + wr][0];
    const u16* Bhl = &SM[cur][wc >> 1][0];
    const u16* Bkvl = &BKV[(kt >> 1) & 1][(kt & 1) * 2048];
    const int rB0 = (wc & 1) * 64;
    auto rdA = [&](int r, int kk) {
      int ch = (kk * 4 + lk) ^ (r & 7);
      return *(const bf16x8*)&Ahl[r * 64 + ch * 8];
    };
    auto rdB = [&](int r, int kk) {
      int ch = (kk * 4 + lk) ^ (r & 7);
      return *(const bf16x8*)&Bhl[r * 64 + ch * 8];
    };
    auto rdBkv = [&](int r, int kk) {
      int ch = (kk * 4 + lk) ^ (r & 7);
      return *(const bf16x8*)&Bkvl[r * 64 + ch * 8];
    };

    bf16x8 bfr[4][2], af[2][2];
    // ---- P0: read B all (8) + A mi01 (4); stage A(kt+1) h0 ----
#pragma unroll
    for (int ni = 0; ni < 4; ++ni)
#pragma unroll
      for (int kk = 0; kk < 2; ++kk)
        bfr[ni][kk] = rdB(rB0 + ni * 16 + lr, kk);
#pragma unroll
    for (int i = 0; i < 2; ++i)
#pragma unroll
      for (int kk = 0; kk < 2; ++kk)
        af[i][kk] = rdA(i * 16 + lr, kk);
    stage_half(Ah0g, kt + 1, &SM[nxt][2][0]);
    __builtin_amdgcn_s_barrier();
    asm volatile("s_waitcnt lgkmcnt(0)");
    __builtin_amdgcn_sched_barrier(0);
    __builtin_amdgcn_s_setprio(1);
#pragma unroll
    for (int i = 0; i < 2; ++i)
#pragma unroll
      for (int ni = 0; ni < 4; ++ni)
#pragma unroll
        for (int kk = 0; kk < 2; ++kk)
          acc[i][ni] = __builtin_amdgcn_mfma_f32_16x16x32_bf16(af[i][kk], bfr[ni][kk], acc[i][ni], 0, 0, 0);
    __builtin_amdgcn_s_setprio(0);
    __builtin_amdgcn_s_barrier();

    // ---- P1: read A mi23 (4) + KV frags (8); stage A(kt+1) h1 + Bkv (even kt);
    //          MFMA: Q mi23 (16) + KV (8) ----
    {
      bf16x8 afkv[2][2], bfkv[2][2];
#pragma unroll
      for (int i = 0; i < 2; ++i)
#pragma unroll
        for (int kk = 0; kk < 2; ++kk)
          af[i][kk] = rdA((2 + i) * 16 + lr, kk);
#pragma unroll
      for (int rg = 0; rg < 2; ++rg)
#pragma unroll
        for (int kk = 0; kk < 2; ++kk)
          afkv[rg][kk] = rdA(wc * 32 + rg * 16 + lr, kk);
#pragma unroll
      for (int cg = 0; cg < 2; ++cg)
#pragma unroll
        for (int kk = 0; kk < 2; ++kk)
          bfkv[cg][kk] = rdBkv(cg * 16 + lr, kk);
      stage_half(Ah1g, kt + 1, &SM[nxt][3][0]);
      if ((kt & 1) == 0) stage_bkv(kt + 2);
      __builtin_amdgcn_s_barrier();
      asm volatile("s_waitcnt lgkmcnt(0)");
      __builtin_amdgcn_sched_barrier(0);
      __builtin_amdgcn_s_setprio(1);
#pragma unroll
      for (int i = 0; i < 2; ++i)
#pragma unroll
        for (int ni = 0; ni < 4; ++ni)
#pragma unroll
          for (int kk = 0; kk < 2; ++kk)
            acc[2 + i][ni] = __builtin_amdgcn_mfma_f32_16x16x32_bf16(af[i][kk], bfr[ni][kk], acc[2 + i][ni], 0, 0, 0);
#pragma unroll
      for (int rg = 0; rg < 2; ++rg)
#pragma unroll
        for (int cg = 0; cg < 2; ++cg)
#pragma unroll
          for (int kk = 0; kk < 2; ++kk)
            acckv[rg][cg] = __builtin_amdgcn_mfma_f32_16x16x32_bf16(afkv[rg][kk], bfkv[cg][kk], acckv[rg][cg], 0, 0, 0);
      __builtin_amdgcn_s_setprio(0);
      __builtin_amdgcn_s_barrier();
    }

    // ---- P2: read A mi45; stage B(kt+2) h0 (B reads done in P0) ----
#pragma unroll
    for (int i = 0; i < 2; ++i)
#pragma unroll
      for (int kk = 0; kk < 2; ++kk)
        af[i][kk] = rdA((4 + i) * 16 + lr, kk);
    stage_half(Bh0g, kt + 2, &SM[cur][0][0]);
    __builtin_amdgcn_s_barrier();
    asm volatile("s_waitcnt lgkmcnt(0)");
    __builtin_amdgcn_sched_barrier(0);
    __builtin_amdgcn_s_setprio(1);
#pragma unroll
    for (int i = 0; i < 2; ++i)
#pragma unroll
      for (int ni = 0; ni < 4; ++ni)
#pragma unroll
        for (int kk = 0; kk < 2; ++kk)
          acc[4 + i][ni] = __builtin_amdgcn_mfma_f32_16x16x32_bf16(af[i][kk], bfr[ni][kk], acc[4 + i][ni], 0, 0, 0);
    __builtin_amdgcn_s_setprio(0);
    __builtin_amdgcn_s_barrier();

    // ---- P3: read A mi67; stage B(kt+2) h1; parity-counted boundary vmcnt ----
#pragma unroll
    for (int i = 0; i < 2; ++i)
#pragma unroll
      for (int kk = 0; kk < 2; ++kk)
        af[i][kk] = rdA((6 + i) * 16 + lr, kk);
    stage_half(Bh1g, kt + 2, &SM[cur][1][0]);
    __builtin_amdgcn_s_barrier();
    asm volatile("s_waitcnt lgkmcnt(0)");
    __builtin_amdgcn_sched_barrier(0);
    __builtin_amdgcn_s_setprio(1);
#pragma unroll
    for (int i = 0; i < 2; ++i)
#pragma unroll
      for (int ni = 0; ni < 4; ++ni)
#pragma unroll
        for (int kk = 0; kk < 2; ++kk)
          acc[6 + i][ni] = __builtin_amdgcn_mfma_f32_16x16x32_bf16(af[i][kk], bfr[ni][kk], acc[6 + i][ni], 0, 0, 0);
    __builtin_amdgcn_s_setprio(0);
    if (kt < NT - 2) {
      if ((kt & 1) == 0) {
        asm volatile("s_waitcnt vmcnt(5)");   // leave B(kt+2)[4] + Bkv[1]
      } else {
        asm volatile("s_waitcnt vmcnt(4)");   // leave B(kt+2)[4]; Bkv forced landed
      }
    } else {
      asm volatile("s_waitcnt vmcnt(0)");
    }
    __builtin_amdgcn_s_barrier();
    __builtin_amdgcn_sched_barrier(0);
  }

  // epilogue: Q scatter (bias) — n always < 4096
#pragma unroll
  for (int ni = 0; ni < 4; ++ni) {
    int n = n0 + wc * 64 + ni * 16 + lr;
    float bv = bias[n];
#pragma unroll
    for (int mi = 0; mi < 8; ++mi) {
      int mb = m0 + wr * 128 + mi * 16 + lk * 4;
#pragma unroll
      for (int j = 0; j < 4; ++j) {
        int m = mb + j;
        int bb = m >> 11;
        int ss = m & 2047;
        u16 hv = f2b(acc[mi][ni][j] + bv);
        Qb[(((size_t)bb * NHh + (n >> 7)) * Ss + ss) * HDd + (n & 127)] = hv;
      }
    }
  }
  // epilogue: KV scatter (bias) — 32 cols per block, 32 rows per wave
#pragma unroll
  for (int rg = 0; rg < 2; ++rg)
#pragma unroll
    for (int cg = 0; cg < 2; ++cg) {
      int kvcol = ntile * 32 + cg * 16 + lr;      // 0..511
      float bv = bias[4096 + kvcol];
#pragma unroll
      for (int j = 0; j < 4; ++j) {
        int m = m0 + wr * 128 + wc * 32 + rg * 16 + lk * 4 + j;
        int bb = m >> 11;
        int ss = m & 2047;
        u16 hv = f2b(acckv[rg][cg][j] + bv);
        if (kvcol < 256) {
          Kb[(((size_t)bb * KVHh + (kvcol >> 7)) * Ss + ss) * HDd + (kvcol & 127)] = hv;
        } else {
          int i2 = kvcol - 256;
          Vb[(((size_t)bb * KVHh + (i2 >> 7)) * Ss + ss) * HDd + (i2 & 127)] = hv;
        }
      }
    }
}

// ---------------- dense GEMM: 256x256 tile, 4-quadrant schedule (R15 form) ----------
__global__ __launch_bounds__(512, 2) void gemm_d256(
    const u16* __restrict__ A, const u16* __restrict__ Bm,
    float* __restrict__ Cout) {
  __shared__ u16 SM[2][4][8192];
  const int tid = threadIdx.x;
  const int wave = tid >> 6;
  const int lane = tid & 63;
  const int lr = lane & 15;
  const int lk = lane >> 4;
  const int wr = wave >> 2;
  const int wc = wave & 3;
  const int bid = blockIdx.x;
  const int xcd = bid & 7;
  const int local = bid >> 3;
  const int m0 = ((xcd >> 2) * 8 + (local >> 2)) * 256;
  const int n0 = ((xcd & 3) * 4 + (local & 3)) * 256;
  const int NT = 64;

  f32x4 acc[8][4];
#pragma unroll
  for (int i = 0; i < 8; ++i)
#pragma unroll
    for (int j = 0; j < 4; ++j) acc[i][j] = (f32x4){0.f, 0.f, 0.f, 0.f};

  auto stage_half = [&](const u16* grows, int j, u16* dst) {
    if (j >= NT) return;
#pragma unroll
    for (int li = 0; li < 2; ++li) {
      int t16 = li * 512 + tid;
      int row = t16 >> 3, c = t16 & 7;
      int cs = c ^ (row & 7);
      gload_lds16(grows + (size_t)row * 4096 + j * 64 + cs * 8, dst + t16 * 8);
    }
  };
  const u16* Ah0g = A + (size_t)m0 * 4096;
  const u16* Ah1g = A + (size_t)(m0 + 128) * 4096;
  const u16* Bh0g = Bm + (size_t)n0 * 4096;
  const u16* Bh1g = Bm + (size_t)(n0 + 128) * 4096;

  stage_half(Ah0g, 0, &SM[0][2][0]);
  stage_half(Ah1g, 0, &SM[0][3][0]);
  stage_half(Bh0g, 0, &SM[0][0][0]);
  stage_half(Bh1g, 0, &SM[0][1][0]);
  stage_half(Bh0g, 1, &SM[1][0][0]);
  stage_half(Bh1g, 1, &SM[1][1][0]);
  asm volatile("s_waitcnt vmcnt(0)");
  __builtin_amdgcn_s_barrier();
  __builtin_amdgcn_sched_barrier(0);

  for (int kt = 0; kt < NT; ++kt) {
    const int cur = kt & 1;
    const int nxt = cur ^ 1;
    const u16* Ahl = &SM[cur][2 + wr][0];
    const u16* Bhl = &SM[cur][wc >> 1][0];
    const int rB0 = (wc & 1) * 64;
    auto rdA = [&](int r, int kk) {
      int ch = (kk * 4 + lk) ^ (r & 7);
      return *(const bf16x8*)&Ahl[r * 64 + ch * 8];
    };
    auto rdB = [&](int r, int kk) {
      int ch = (kk * 4 + lk) ^ (r & 7);
      return *(const bf16x8*)&Bhl[r * 64 + ch * 8];
    };

    bf16x8 bfr[4][2], af[2][2];
#pragma unroll
    for (int ni = 0; ni < 4; ++ni)
#pragma unroll
      for (int kk = 0; kk < 2; ++kk)
        bfr[ni][kk] = rdB(rB0 + ni * 16 + lr, kk);
#pragma unroll
    for (int i = 0; i < 2; ++i)
#pragma unroll
      for (int kk = 0; kk < 2; ++kk)
        af[i][kk] = rdA(i * 16 + lr, kk);
    stage_half(Ah0g, kt + 1, &SM[nxt][2][0]);
    __builtin_amdgcn_s_barrier();
    asm volatile("s_waitcnt lgkmcnt(0)");
    __builtin_amdgcn_sched_barrier(0);
    __builtin_amdgcn_s_setprio(1);
#pragma unroll
    for (int i = 0; i < 2; ++i)
#pragma unroll
      for (int ni = 0; ni < 4; ++ni)
#pragma unroll
        for (int kk = 0; kk < 2; ++kk)
          acc[i][ni] = __builtin_amdgcn_mfma_f32_16x16x32_bf16(af[i][kk], bfr[ni][kk], acc[i][ni], 0, 0, 0);
    __builtin_amdgcn_s_setprio(0);
    __builtin_amdgcn_s_barrier();

#pragma unroll
    for (int i = 0; i < 2; ++i)
#pragma unroll
      for (int kk = 0; kk < 2; ++kk)
        af[i][kk] = rdA((2 + i) * 16 + lr, kk);
    stage_half(Ah1g, kt + 1, &SM[nxt][3][0]);
    __builtin_amdgcn_s_barrier();
    asm volatile("s_waitcnt lgkmcnt(0)");
    __builtin_amdgcn_sched_barrier(0);
    __builtin_amdgcn_s_setprio(1);
#pragma unroll
    for (int i = 0; i < 2; ++i)
#pragma unroll
      for (int ni = 0; ni < 4; ++ni)
#pragma unroll
        for (int kk = 0; kk < 2; ++kk)
          acc[2 + i][ni] = __builtin_amdgcn_mfma_f32_16x16x32_bf16(af[i][kk], bfr[ni][kk], acc[2 + i][ni], 0, 0, 0);
    __builtin_amdgcn_s_setprio(0);
    __builtin_amdgcn_s_barrier();

#pragma unroll
    for (int i = 0; i < 2; ++i)
#pragma unroll
      for (int kk = 0; kk < 2; ++kk)
        af[i][kk] = rdA((4 + i) * 16 + lr, kk);
    stage_half(Bh0g, kt + 2, &SM[cur][0][0]);
    __builtin_amdgcn_s_barrier();
    asm volatile("s_waitcnt lgkmcnt(0)");
    __builtin_amdgcn_sched_barrier(0);
    __builtin_amdgcn_s_setprio(1);
#pragma unroll
    for (int i = 0; i < 2; ++i)
#pragma unroll
      for (int ni = 0; ni < 4; ++ni)
#pragma unroll
        for (int kk = 0; kk < 2; ++kk)
          acc[4 + i][ni] = __builtin_amdgcn_mfma_f32_16x16x32_bf16(af[i][kk], bfr[ni][kk], acc[4 + i][ni], 0, 0, 0);
    __builtin_amdgcn_s_setprio(0);
    __builtin_amdgcn_s_barrier();

#pragma unroll
    for (int i = 0; i < 2; ++i)
#pragma unroll
      for (int kk = 0; kk < 2; ++kk)
        af[i][kk] = rdA((6 + i) * 16 + lr, kk);
    stage_half(Bh1g, kt + 2, &SM[cur][1][0]);
    __builtin_amdgcn_s_barrier();
    asm volatile("s_waitcnt lgkmcnt(0)");
    __builtin_amdgcn_sched_barrier(0);
    __builtin_amdgcn_s_setprio(1);
#pragma unroll
    for (int i = 0; i < 2; ++i)
#pragma unroll
      for (int ni = 0; ni < 4; ++ni)
#pragma unroll
        for (int kk = 0; kk < 2; ++kk)
          acc[6 + i][ni] = __builtin_amdgcn_mfma_f32_16x16x32_bf16(af[i][kk], bfr[ni][kk], acc[6 + i][ni], 0, 0, 0);
    __builtin_amdgcn_s_setprio(0);
    if (kt < NT - 2) {
      asm volatile("s_waitcnt vmcnt(4)");
    } else {
      asm volatile("s_waitcnt vmcnt(0)");
    }
    __builtin_amdgcn_s_barrier();
    __builtin_amdgcn_sched_barrier(0);
  }

#pragma unroll
  for (int mi = 0; mi < 8; ++mi)
#pragma unroll
    for (int ni = 0; ni < 4; ++ni) {
      int col = n0 + wc * 64 + ni * 16 + lr;
      int rowb = m0 + wr * 128 + mi * 16 + lk * 4;
#pragma unroll
      for (int j = 0; j < 4; ++j)
        Cout[(size_t)(rowb + j) * 4096 + col] = acc[mi][ni][j];
    }
}

// ---------------- causal GQA flash attention, 8-wave 32x32 swapped-QK^T ----------------
// grid (4, NH, B): block x processes q-tile PAIR {7-x, x}. T5 setprio added around
// both MFMA clusters (measured +4-7% on attn, m191: blocks progress independently
// on the same CU, unlike barrier-locked GEMMs).
__global__ __launch_bounds__(512, 2) void attn_k(
    const u16* __restrict__ Qb, const u16* __restrict__ Kb,
    const u16* __restrict__ Vb, const float* __restrict__ rope,
    u16* __restrict__ Ctx) {
  __shared__ u16 Kt[2][64 * 128];
  __shared__ u16 Vt[2][128 * 64];
  const int tid = threadIdx.x;
  const int w = tid >> 6;
  const int lane = tid & 63;
  const int l31 = lane & 31;
  const int hi = lane >> 5;
  const int h = blockIdx.y, b = blockIdx.z;
  const int hkv = h >> 4;
  const u16* Qp = Qb + ((size_t)(b * NHh + h)) * Ss * HDd;
  const u16* Kp = Kb + ((size_t)(b * KVHh + hkv)) * Ss * HDd;
  const u16* Vp = Vb + ((size_t)(b * KVHh + hkv)) * Ss * HDd;

  const float scale = 0.08838834764831845f;
  const float L2E = 1.4426950408889634f;

  for (int hp = 0; hp < 2; ++hp) {
    const int qt = hp == 0 ? (7 - (int)blockIdx.x) : (int)blockIdx.x;
    const int qs = qt * 256;
    const int qw = qs + w * 32;
    const int qrow = qw + l31;
    const int nt = qs / 64 + 4;

    bf16x8 qf[8];
#pragma unroll
    for (int ds = 0; ds < 8; ++ds)
      qf[ds] = *(const bf16x8*)&Qp[(size_t)qrow * HDd + ds * 16 + hi * 8];
#pragma unroll
    for (int ds = 0; ds < 4; ++ds) {
      bf16x8 q = qf[ds];
      bf16x8 o;
#pragma unroll
      for (int i = 0; i < 4; ++i) {
        int p = ds * 8 + hi * 4 + i;
        float2 rc = *(const float2*)&rope[(((size_t)b * Ss + qrow) * 32 + p) * 2];
        float x0 = b2f((u16)q[2 * i]), x1 = b2f((u16)q[2 * i + 1]);
        o[2 * i] = (short)f2b(x0 * rc.x - x1 * rc.y);
        o[2 * i + 1] = (short)f2b(x1 * rc.x + x0 * rc.y);
      }
      qf[ds] = o;
    }

    f32x16 accO[4];
#pragma unroll
    for (int i = 0; i < 4; ++i)
#pragma unroll
      for (int r = 0; r < 16; ++r) accO[i][r] = 0.f;
    float m_r = -3.0e38f, l_r = 0.f;

    {
#pragma unroll
      for (int i = 0; i < 2; ++i) {
        int slot = w * 2 + i;
        int r = slot * 4 + (lane >> 4);
        int p = lane & 15;
        int gc = (p & 8) | ((p ^ r) & 7);
        gload_lds16(Kp + (size_t)r * HDd + gc * 8, &Kt[0][slot * 512]);
      }
      bf16x8 v0 = *(const bf16x8*)&Vp[(size_t)lane * HDd + w * 16];
      bf16x8 v1 = *(const bf16x8*)&Vp[(size_t)lane * HDd + w * 16 + 8];
      u32x4 sv = __builtin_bit_cast(u32x4, (lane & 1) ? v0 : v1);
      u32x4 rv;
      rv.x = __shfl_xor(sv.x, 1); rv.y = __shfl_xor(sv.y, 1);
      rv.z = __shfl_xor(sv.z, 1); rv.w = __shfl_xor(sv.w, 1);
      bf16x8 recv = __builtin_bit_cast(bf16x8, rv);
      int kvp = lane >> 1;
#pragma unroll
      for (int i = 0; i < 8; ++i) {
        int d = w * 16 + (lane & 1) * 8 + i;
        u16 lo = (lane & 1) ? (u16)recv[i] : (u16)v0[i];
        u16 hb = (lane & 1) ? (u16)v1[i] : (u16)recv[i];
        u32 val = (u32)lo | ((u32)hb << 16);
        int cp = (kvp >> 2) ^ (d & 7);
        *(u32*)&Vt[0][d * 64 + cp * 8 + (kvp & 3) * 2] = val;
      }
    }
    __syncthreads();

    for (int t = 0; t < nt; ++t) {
      const int j0 = t * 64;
      const int cur = t & 1;
      const bool havenext = (t + 1 < nt);
      bf16x8 nv0, nv1;
      if (havenext) {
        const int j1 = j0 + 64;
#pragma unroll
        for (int i = 0; i < 2; ++i) {
          int slot = w * 2 + i;
          int r = slot * 4 + (lane >> 4);
          int p = lane & 15;
          int gc = (p & 8) | ((p ^ r) & 7);
          gload_lds16(Kp + (size_t)(j1 + r) * HDd + gc * 8, &Kt[cur ^ 1][slot * 512]);
        }
        nv0 = *(const bf16x8*)&Vp[(size_t)(j1 + lane) * HDd + w * 16];
        nv1 = *(const bf16x8*)&Vp[(size_t)(j1 + lane) * HDd + w * 16 + 8];
      }

      if (j0 <= qw + 31) {
        f32x16 aS[2];
#pragma unroll
        for (int a = 0; a < 2; ++a)
#pragma unroll
          for (int r = 0; r < 16; ++r) aS[a][r] = 0.f;
        __builtin_amdgcn_s_setprio(1);
#pragma unroll
        for (int kvb = 0; kvb < 2; ++kvb) {
          int r = kvb * 32 + l31;
#pragma unroll
          for (int ds = 0; ds < 8; ++ds) {
            int c = ds * 2 + hi;
            int cp = (c & 8) | ((c ^ r) & 7);
            bf16x8 kf = *(const bf16x8*)&Kt[cur][r * 128 + cp * 8];
            aS[kvb] = __builtin_amdgcn_mfma_f32_32x32x16_bf16(kf, qf[ds], aS[kvb], 0, 0, 0);
          }
        }
        __builtin_amdgcn_s_setprio(0);
        const bool needmask = (j0 + 63 > qw);
        float mx = -3.0e38f;
#pragma unroll
        for (int a = 0; a < 2; ++a)
#pragma unroll
          for (int r = 0; r < 16; ++r) {
            float s = aS[a][r] * scale;
            if (needmask) {
              int kv = j0 + a * 32 + (r & 3) + 8 * (r >> 2) + 4 * hi;
              s = (kv > qrow) ? -3.0e38f : s;
            }
            aS[a][r] = s;
            mx = fmaxf(mx, s);
          }
        mx = fmaxf(mx, __shfl_xor(mx, 32));
        if (!__all(mx - m_r <= 8.0f)) {
          float mnew = fmaxf(m_r, mx);
          float corr = __builtin_amdgcn_exp2f((m_r - mnew) * L2E);
          l_r *= corr;
#pragma unroll
          for (int i = 0; i < 4; ++i)
#pragma unroll
            for (int r = 0; r < 16; ++r) accO[i][r] *= corr;
          m_r = mnew;
        }
        float sum = 0.f;
#pragma unroll
        for (int a = 0; a < 2; ++a)
#pragma unroll
          for (int r = 0; r < 16; ++r) {
            float pe = __builtin_amdgcn_exp2f((aS[a][r] - m_r) * L2E);
            aS[a][r] = pe;
            sum += pe;
          }
        sum += __shfl_xor(sum, 32);
        l_r += sum;

        u32 cc0[2][4], cc1[2][4];
#pragma unroll
        for (int a = 0; a < 2; ++a)
#pragma unroll
          for (int g = 0; g < 4; ++g) {
            cc0[a][g] = cvtpk(aS[a][g * 4 + 0], aS[a][g * 4 + 1]);
            cc1[a][g] = cvtpk(aS[a][g * 4 + 2], aS[a][g * 4 + 3]);
          }
        bf16x8 pa[4];
#pragma unroll
        for (int ks = 0; ks < 4; ++ks) {
          int a = ks >> 1, g0 = (ks & 1) * 2;
          u32 w0 = cc0[a][g0], w2 = cc0[a][g0 + 1];
          u32 w1 = cc1[a][g0], w3 = cc1[a][g0 + 1];
          plswap(w0, w2);
          plswap(w1, w3);
          u32x4 tv; tv.x = w0; tv.y = w1; tv.z = w2; tv.w = w3;
          pa[ks] = __builtin_bit_cast(bf16x8, tv);
        }
        __builtin_amdgcn_s_setprio(1);
#pragma unroll
        for (int dblk = 0; dblk < 4; ++dblk) {
          int d = dblk * 32 + l31;
#pragma unroll
          for (int ks = 0; ks < 4; ++ks) {
            int c = ks * 2 + hi;
            int cp = c ^ (d & 7);
            bf16x8 vf = *(const bf16x8*)&Vt[cur][d * 64 + cp * 8];
            accO[dblk] = __builtin_amdgcn_mfma_f32_32x32x16_bf16(vf, pa[ks], accO[dblk], 0, 0, 0);
          }
        }
        __builtin_amdgcn_s_setprio(0);
      }

      if (havenext) {
        u32x4 sv = __builtin_bit_cast(u32x4, (lane & 1) ? nv0 : nv1);
        u32x4 rv;
        rv.x = __shfl_xor(sv.x, 1); rv.y = __shfl_xor(sv.y, 1);
        rv.z = __shfl_xor(sv.z, 1); rv.w = __shfl_xor(sv.w, 1);
        bf16x8 recv = __builtin_bit_cast(bf16x8, rv);
        int kvp = lane >> 1;
#pragma unroll
        for (int i = 0; i < 8; ++i) {
          int d = w * 16 + (lane & 1) * 8 + i;
          u16 lo = (lane & 1) ? (u16)recv[i] : (u16)nv0[i];
          u16 hb = (lane & 1) ? (u16)nv1[i] : (u16)recv[i];
          u32 val = (u32)lo | ((u32)hb << 16);
          int cp = (kvp >> 2) ^ (d & 7);
          *(u32*)&Vt[cur ^ 1][d * 64 + cp * 8 + (kvp & 3) * 2] = val;
        }
      }
      __syncthreads();
    }

    {
      float il = 1.0f / l_r;
      size_t rb = ((size_t)b * Ss + qrow) * (size_t)(NHh * HDd) + (size_t)h * HDd;
#pragma unroll
      for (int dblk = 0; dblk < 4; ++dblk)
#pragma unroll
        for (int g = 0; g < 4; ++g) {
          int d0 = dblk * 32 + g * 8 + hi * 4;
          u64 pack = (u64)f2b(accO[dblk][g * 4 + 0] * il) |
                     ((u64)f2b(accO[dblk][g * 4 + 1] * il) << 16) |
                     ((u64)f2b(accO[dblk][g * 4 + 2] * il) << 32) |
                     ((u64)f2b(accO[dblk][g * 4 + 3] * il) << 48);
          *(u64*)&Ctx[rb + d0] = pack;
        }
    }
    __syncthreads();
  }
}

extern "C" void kernel_launch(void* const* d_in, const int* in_sizes, int n_in,
                              void* d_out, int out_size, void* d_ws, size_t ws_size,
                              hipStream_t stream) {
  const float* hidden = (const float*)d_in[0];
  const float* rope = (const float*)d_in[1];
  const float* Wqkv = (const float*)d_in[3];
  const float* bqkv = (const float*)d_in[4];
  const float* Wdense = (const float*)d_in[5];
  float* out = (float*)d_out;

  // ws layout: 104 MB total (L3-friendly).
  char* w = (char*)d_ws;
  u16* Xbf = (u16*)w;
  u16* ctx = Xbf;
  w += (size_t)33554432;
  u16* Wq = (u16*)w;
  u16* Wd = Wq;                        // alias: written AFTER QKV GEMM consumed Wq
  w += (size_t)37748736;
  u16* Qb = (u16*)w; w += (size_t)33554432;
  u16* Kb = (u16*)w; w += (size_t)2097152;
  u16* Vb = (u16*)w; w += (size_t)2097152;

  // 1. fused convert: hidden->Xbf, Wqkv->Wq
  cvt2_k<<<34816, 256, 0, stream>>>(hidden, Xbf, Wqkv, Wq);
  // 2. QKV GEMM: d256 schedule + fused KV side-work; 256 blocks, 1/CU, no tail
  gemm_qkv256<<<dim3(256), 512, 0, stream>>>(Xbf, Wq, bqkv, Qb, Kb, Vb);
  // 3. RoPE on K only (Q's rope fused into attn_k)
  rope_k<<<(Bb * KVHh * Ss * 32 + 255) / 256, 256, 0, stream>>>(Kb, rope, KVHh);
  // 4. convert Wdense into Wq's region
  cvtW_k<<<16384, 256, 0, stream>>>(Wdense, Wd);
  // 5. flash attention (balanced causal pairing, fused Q-RoPE, T5 setprio)
  attn_k<<<dim3(4, NHh, Bb), 512, 0, stream>>>(Qb, Kb, Vb, rope, ctx);
  // 6. dense GEMM: 256^2 4-quadrant schedule; 256 blocks (1/CU)
  gemm_d256<<<dim3(256), 512, 0, stream>>>(ctx, Wd, out);
}